// Round 10
// baseline (63.239 us; speedup 1.0000x reference)
//
#include <hip/hip_runtime.h>
#include <hip/hip_bf16.h>
#include <stdint.h>

// Problem constants (fixed by the reference)
#define B_SZ 8192
#define D_SZ 256
#define R_SZ 8
#define N_SZ 1024
#define C_SZ (B_SZ / R_SZ)          // 1024
#define CN   (C_SZ * N_SZ)          // 1048576
#define L_SZ (B_SZ + 2 * R_SZ * CN) // 16785408 (logits length)
#define BD   (B_SZ * D_SZ)          // 2097152 elems per ws array

typedef short bf16x8 __attribute__((ext_vector_type(8)));
typedef float f32x4  __attribute__((ext_vector_type(4)));

static __device__ __forceinline__ unsigned short f2bf(float f) {
  unsigned u = __float_as_uint(f);
  u += 0x7FFFu + ((u >> 16) & 1u);   // RNE
  return (unsigned short)(u >> 16);
}
static __device__ __forceinline__ float bf2f(unsigned short h) {
  return __uint_as_float(((unsigned)h) << 16);
}
static __device__ __forceinline__ float sigmoidf_(float x) {
  return 1.0f / (1.0f + __expf(-x));
}
static __device__ __forceinline__ void gload16(const void* g, void* l) {
  __builtin_amdgcn_global_load_lds(
      (const __attribute__((address_space(1))) void*)g,
      (__attribute__((address_space(3))) void*)l, 16, 0, 0);
}

// ws layout (bytes), SORTED by relation (row p = r*1024 + c):
//   0    : lhs_hi_s (4MB)
//   4MB  : lhs_lo_s
//   8MB  : rhs_hi_s
//   12MB : rhs_lo_s
//   16MB : inv (32KB int)   inv[order[j]] = j

// ---------------------------------------------------------------------------
__global__ void inv_kernel(const int* __restrict__ order, int* __restrict__ inv) {
  int j = blockIdx.x * 256 + threadIdx.x;
  inv[order[j]] = j;
}

// ---------------------------------------------------------------------------
// Phase 1: F-reduce emb -> lhs/rhs, split bf16 hi+lo, SCATTER to sorted rows.
// One wave per batch row i. 2048 blocks x 256 threads. (~9 us, BW-bound.)
// ---------------------------------------------------------------------------
__global__ __launch_bounds__(256) void prep_kernel(
    const float* __restrict__ emb, const float* __restrict__ trans,
    const int* __restrict__ rels, const int* __restrict__ inv,
    float* __restrict__ out, unsigned short* __restrict__ sortArr) {
  unsigned short* lhs_hi = sortArr;
  unsigned short* lhs_lo = sortArr + (size_t)BD;
  unsigned short* rhs_hi = sortArr + (size_t)2 * BD;
  unsigned short* rhs_lo = sortArr + (size_t)3 * BD;

  int wave = threadIdx.x >> 6;
  int lane = threadIdx.x & 63;
  int i = blockIdx.x * 4 + wave;            // 0..B-1

  const float4* emb4 = (const float4*)emb;  // emb row j = 128 float4 (F*D=512 f32)
  size_t bl = (size_t)(2 * i) * 128;
  size_t br = (size_t)(2 * i + 1) * 128;
  float4 a0 = emb4[bl + lane];
  float4 a1 = emb4[bl + 64 + lane];
  float4 b0 = emb4[br + lane];
  float4 b1 = emb4[br + 64 + lane];
  float lh[4] = {a0.x + a1.x, a0.y + a1.y, a0.z + a1.z, a0.w + a1.w};
  float rh[4] = {b0.x + b1.x, b0.y + b1.y, b0.z + b1.z, b0.w + b1.w};

  int rel = rels[i];
  float4 tv = ((const float4*)trans)[rel * 64 + lane];
  float tt[4] = {tv.x, tv.y, tv.z, tv.w};

  float p = 0.f;
#pragma unroll
  for (int j = 0; j < 4; ++j) p += lh[j] * (rh[j] + tt[j]);
#pragma unroll
  for (int off = 32; off; off >>= 1) p += __shfl_xor(p, off, 64);
  if (lane == 0) {
    out[i] = p;
    out[(size_t)L_SZ + i] = sigmoidf_(p);
  }

  int sp = inv[i];  // sorted row
  unsigned short h[4], l[4];
#pragma unroll
  for (int j = 0; j < 4; ++j) {
    h[j] = f2bf(lh[j]);
    l[j] = f2bf(lh[j] - bf2f(h[j]));
  }
  *(ushort4*)(lhs_hi + (size_t)sp * 256 + lane * 4) = make_ushort4(h[0], h[1], h[2], h[3]);
  *(ushort4*)(lhs_lo + (size_t)sp * 256 + lane * 4) = make_ushort4(l[0], l[1], l[2], l[3]);
#pragma unroll
  for (int j = 0; j < 4; ++j) {
    h[j] = f2bf(rh[j]);
    l[j] = f2bf(rh[j] - bf2f(h[j]));
  }
  *(ushort4*)(rhs_hi + (size_t)sp * 256 + lane * 4) = make_ushort4(h[0], h[1], h[2], h[3]);
  *(ushort4*)(rhs_lo + (size_t)sp * 256 + lane * 4) = make_ushort4(l[0], l[1], l[2], l[3]);
}

// ---------------------------------------------------------------------------
// Phase 2: negatives GEMM, 256x256 tile, 8 waves (2x4), BK=32, single-buffer
// 64 KB LDS (Ah/Al/Bh/Bl x 256 rows x 64B), grid 256 (1/CU), PROVEN 2-barrier
// schedule: stage -> syncthreads -> compute -> syncthreads, 8 cycles.
// Halves per-CU staged bytes vs the 128^2 version (each staged byte feeds 2x
// the MFMA). r == XCD swizzle + sorted layout -> per-XCD 4MB L2-local reads.
// Split-bf16: acc += Ah*Bh + Al*Bh + Ah*Bl. XOR chunk swizzle (<=2-way, free).
// ---------------------------------------------------------------------------
__global__ __launch_bounds__(512, 2) void negs_kernel(
    const unsigned short* __restrict__ ws, const int* __restrict__ inv,
    const int* __restrict__ negL, const int* __restrict__ negR,
    float* __restrict__ out) {
  __shared__ char lds[4][16384];  // Ah, Al, Bh, Bl ; 256 rows x 64 B each

  const char* base0 = (const char*)ws;

  int hw = blockIdx.x;
  int bid = (hw & 7) * 32 + (hw >> 3);   // bijective: 256 = 8 XCD x 32; r == XCD
  int ntile = bid & 3;
  int ctile = (bid >> 2) & 3;
  int side  = (bid >> 4) & 1;
  int r     = bid >> 5;

  int t = threadIdx.x;
  int wave = t >> 6, lane = t & 63;
  int wrow = wave >> 2, wcol = wave & 3;   // 2 x 4 wave grid, 128x64 out each
  int lx = lane & 15;

  // side 0: A = s_rhs, B = samp_lhs ; side 1: A = s_lhs, B = samp_rhs
  const char* aHi = base0 + (side ? 0 : ((size_t)8 << 20));
  const char* aLo = aHi + ((size_t)4 << 20);
  const char* bHi = base0 + (side ? ((size_t)8 << 20) : 0);
  const char* bLo = bHi + ((size_t)4 << 20);
  const int* negp = side ? negR : negL;

  // Staging: wave w stages array w>>1 (0=Ah 1=Al 2=Bh 3=Bl), row-half (w&1)*128.
  // Load 'it' covers panel rows (w&1)*128 + it*16 + (lane>>2), chunk lane&3.
  // Source chunk inverse-swizzled: (lane&3) ^ ((row>>1)&3) = (lane&3)^((lane>>3)&3).
  int arr = wave >> 1;
  const char* srcp = (arr == 0) ? aHi : (arr == 1) ? aLo : (arr == 2) ? bHi : bLo;
  unsigned srcswz = (unsigned)(((lane & 3) ^ ((lane >> 3) & 3)) << 4);
  unsigned goff[8];
  {
    int prow0 = (wave & 1) * 128 + (lane >> 2);
    if (arr < 2) {
      int grow = r * C_SZ + ctile * 256 + prow0;
#pragma unroll
      for (int it = 0; it < 8; ++it)
        goff[it] = (unsigned)(grow + it * 16) * 512u + srcswz;
    } else {
      int nb = r * N_SZ + ntile * 256 + prow0;
#pragma unroll
      for (int it = 0; it < 8; ++it)
        goff[it] = (unsigned)inv[negp[nb + it * 16]] * 512u + srcswz;
    }
  }
  char* myLds = &lds[arr][0] + (wave & 1) * 8192;

  f32x4 acc[8][4] = {};
  int q = lane >> 4;                       // logical 16B chunk 0..3 in 64B row
  int rsw = ((q ^ ((lx >> 1) & 3)) << 4);  // swizzled read chunk (lane-const)

#pragma unroll 1
  for (int kc = 0; kc < 8; ++kc) {
#pragma unroll
    for (int it = 0; it < 8; ++it)
      gload16(srcp + goff[it] + (unsigned)kc * 64u, myLds + it * 1024);
    __syncthreads();

    bf16x8 ah[8], al_[8], bh[4], bl_[4];
#pragma unroll
    for (int mi = 0; mi < 8; ++mi) {
      int off = (wrow * 128 + mi * 16 + lx) * 64 + rsw;
      ah[mi]  = *(const bf16x8*)(&lds[0][0] + off);
      al_[mi] = *(const bf16x8*)(&lds[1][0] + off);
    }
#pragma unroll
    for (int ni = 0; ni < 4; ++ni) {
      int off = (wcol * 64 + ni * 16 + lx) * 64 + rsw;
      bh[ni]  = *(const bf16x8*)(&lds[2][0] + off);
      bl_[ni] = *(const bf16x8*)(&lds[3][0] + off);
    }
#pragma unroll
    for (int mi = 0; mi < 8; ++mi)
#pragma unroll
      for (int ni = 0; ni < 4; ++ni) {
        acc[mi][ni] = __builtin_amdgcn_mfma_f32_16x16x32_bf16(ah[mi],  bh[ni],  acc[mi][ni], 0, 0, 0);
        acc[mi][ni] = __builtin_amdgcn_mfma_f32_16x16x32_bf16(al_[mi], bh[ni],  acc[mi][ni], 0, 0, 0);
        acc[mi][ni] = __builtin_amdgcn_mfma_f32_16x16x32_bf16(ah[mi],  bl_[ni], acc[mi][ni], 0, 0, 0);
      }
    __syncthreads();
  }

  // Epilogue: contiguous-row stores. C/D layout col = lane&15, row = (lane>>4)*4+jj.
  size_t obase = (size_t)B_SZ + (size_t)(r * 2 + side) * CN;
  int gcb = ntile * 256 + wcol * 64 + lx;
  int grb = ctile * 256 + wrow * 128 + ((lane >> 4) << 2);
#pragma unroll
  for (int mi = 0; mi < 8; ++mi) {
#pragma unroll
    for (int ni = 0; ni < 4; ++ni) {
      int gc = gcb + ni * 16;
#pragma unroll
      for (int jj = 0; jj < 4; ++jj) {
        int gr = grb + mi * 16 + jj;
        size_t idx = obase + (size_t)gr * N_SZ + gc;
        float v = acc[mi][ni][jj];
        out[idx] = v;
        out[(size_t)L_SZ + idx] = sigmoidf_(v);
      }
    }
  }
}

// ---------------------------------------------------------------------------
extern "C" void kernel_launch(void* const* d_in, const int* in_sizes, int n_in,
                              void* d_out, int out_size, void* d_ws, size_t ws_size,
                              hipStream_t stream) {
  const float* emb   = (const float*)d_in[0];
  const float* trans = (const float*)d_in[1];
  const int*   rels  = (const int*)d_in[2];
  const int*   order = (const int*)d_in[3];
  const int*   negL  = (const int*)d_in[4];
  const int*   negR  = (const int*)d_in[5];
  float* out = (float*)d_out;

  unsigned short* sortArr = (unsigned short*)d_ws;
  int* inv = (int*)((char*)d_ws + (size_t)16 * 1024 * 1024);

  inv_kernel<<<32, 256, 0, stream>>>(order, inv);
  prep_kernel<<<B_SZ / 4, 256, 0, stream>>>(emb, trans, rels, inv, out, sortArr);
  negs_kernel<<<256, 512, 0, stream>>>(sortArr, inv, negL, negR, out);
}